// Round 1
// baseline (5559.323 us; speedup 1.0000x reference)
//
#include <hip/hip_runtime.h>
#include <hip/hip_bf16.h>

#define D 64
#define EPS 1e-5f

// ---------------------------------------------------------------------------
// Wave-per-row GEMM (D x D), feature-per-lane. Lane j holds W[:, j] in VGPRs.
// Row data is wave-uniform -> scalar loads (s_load) feed v_fmac with SGPR src.
// Accumulates BN batch stats (sum, sumsq per feature) via one atomicAdd/wave.
// ---------------------------------------------------------------------------
__global__ void __launch_bounds__(256) gemm_relu_stats_kernel(
    const float* __restrict__ in,   // [nrows, 64]
    const float* __restrict__ W,    // [64, 64]
    const float* __restrict__ b,    // [64]
    int nrows,
    float* __restrict__ stats)      // [128]: sum[64], sumsq[64]
{
    const int lane = threadIdx.x & 63;
    const int gtid = blockIdx.x * blockDim.x + threadIdx.x;
    const int wave = __builtin_amdgcn_readfirstlane(gtid >> 6);
    const int nwaves = (gridDim.x * blockDim.x) >> 6;

    float w[D];
#pragma unroll
    for (int k = 0; k < D; ++k) w[k] = W[k * D + lane];
    const float bj = b[lane];

    float s = 0.f, sq = 0.f;
    for (int r = wave; r < nrows; r += nwaves) {
        const float* __restrict__ row = in + (size_t)r * D;  // wave-uniform
        float a0 = bj, a1 = 0.f, a2 = 0.f, a3 = 0.f;
#pragma unroll
        for (int k = 0; k < D; k += 4) {
            a0 = fmaf(row[k + 0], w[k + 0], a0);
            a1 = fmaf(row[k + 1], w[k + 1], a1);
            a2 = fmaf(row[k + 2], w[k + 2], a2);
            a3 = fmaf(row[k + 3], w[k + 3], a3);
        }
        float h = fmaxf((a0 + a1) + (a2 + a3), 0.f);
        s += h;
        sq = fmaf(h, h, sq);
    }
    atomicAdd(&stats[lane], s);
    atomicAdd(&stats[D + lane], sq);
}

// ---------------------------------------------------------------------------
// Finalize BN stats for both paths: scale = g*rsqrt(var+eps), shift = be-m*scale
// threads 0..63 -> atom, 64..127 -> pair
// ---------------------------------------------------------------------------
__global__ void finalize_stats_kernel(
    const float* __restrict__ stats,   // [256]: atom sum/sq, pair sum/sq
    const float* __restrict__ g_a, const float* __restrict__ be_a,
    const float* __restrict__ g_p, const float* __restrict__ be_p,
    float n_atom, float n_pair,
    float* __restrict__ params)        // [256]: atom scale/shift, pair scale/shift
{
    const int t = threadIdx.x;
    const int j = t & 63;
    const bool p = t >= 64;
    const float* st = stats + (p ? 2 * D : 0);
    const float* g  = p ? g_p  : g_a;
    const float* be = p ? be_p : be_a;
    const float cnt = p ? n_pair : n_atom;
    float m = st[j] / cnt;
    float v = st[D + j] / cnt - m * m;
    float sc = g[j] * rsqrtf(v + EPS);
    float sh = be[j] - m * sc;
    float* pr = params + (p ? 2 * D : 0);
    pr[j] = sc;
    pr[D + j] = sh;
}

// ---------------------------------------------------------------------------
// Atom pass 2: recompute h = relu(x @ W + b), apply BN affine, write out.
// ---------------------------------------------------------------------------
__global__ void __launch_bounds__(256) gemm_relu_bn_kernel(
    const float* __restrict__ in, const float* __restrict__ W,
    const float* __restrict__ b, int nrows,
    const float* __restrict__ params,   // [128]: scale, shift
    float* __restrict__ out)
{
    const int lane = threadIdx.x & 63;
    const int gtid = blockIdx.x * blockDim.x + threadIdx.x;
    const int wave = __builtin_amdgcn_readfirstlane(gtid >> 6);
    const int nwaves = (gridDim.x * blockDim.x) >> 6;

    float w[D];
#pragma unroll
    for (int k = 0; k < D; ++k) w[k] = W[k * D + lane];
    const float bj = b[lane];
    const float sc = params[lane];
    const float sh = params[D + lane];

    for (int r = wave; r < nrows; r += nwaves) {
        const float* __restrict__ row = in + (size_t)r * D;
        float a0 = bj, a1 = 0.f, a2 = 0.f, a3 = 0.f;
#pragma unroll
        for (int k = 0; k < D; k += 4) {
            a0 = fmaf(row[k + 0], w[k + 0], a0);
            a1 = fmaf(row[k + 1], w[k + 1], a1);
            a2 = fmaf(row[k + 2], w[k + 2], a2);
            a3 = fmaf(row[k + 3], w[k + 3], a3);
        }
        float h = fmaxf((a0 + a1) + (a2 + a3), 0.f);
        out[(size_t)r * D + lane] = fmaf(h, sc, sh);
    }
}

// ---------------------------------------------------------------------------
// Pair pass 2: per edge e (one wave per edge):
//   out[e] = bn(relu(pf[e] @ W_pair + b_pair)) + [x[send]||x[recv]] @ W_a2p + b_a2p
// Gathered x rows are wave-uniform -> scalar loads through K-cache/L2.
// ---------------------------------------------------------------------------
__global__ void __launch_bounds__(256) pair_out_kernel(
    const float* __restrict__ pf, const float* __restrict__ x,
    const int* __restrict__ pidx,
    const float* __restrict__ Wp, const float* __restrict__ bp,
    const float* __restrict__ Wa, const float* __restrict__ ba,
    int E,
    const float* __restrict__ params,   // [128]: pair scale, shift
    float* __restrict__ out)
{
    const int lane = threadIdx.x & 63;
    const int gtid = blockIdx.x * blockDim.x + threadIdx.x;
    const int wave = __builtin_amdgcn_readfirstlane(gtid >> 6);
    const int nwaves = (gridDim.x * blockDim.x) >> 6;

    float wp[D];
#pragma unroll
    for (int k = 0; k < D; ++k) wp[k] = Wp[k * D + lane];
    float wa[2 * D];
#pragma unroll
    for (int k = 0; k < 2 * D; ++k) wa[k] = Wa[k * D + lane];
    const float bpj = bp[lane];
    const float baj = ba[lane];
    const float sc = params[lane];
    const float sh = params[D + lane];

    for (int e = wave; e < E; e += nwaves) {
        const int is = pidx[e];          // wave-uniform scalar load
        const int ir = pidx[E + e];
        const float* __restrict__ row = pf + (size_t)e * D;

        // h2 = relu(pf @ Wp + bp), then BN affine
        float a0 = bpj, a1 = 0.f, a2 = 0.f, a3 = 0.f;
#pragma unroll
        for (int k = 0; k < D; k += 4) {
            a0 = fmaf(row[k + 0], wp[k + 0], a0);
            a1 = fmaf(row[k + 1], wp[k + 1], a1);
            a2 = fmaf(row[k + 2], wp[k + 2], a2);
            a3 = fmaf(row[k + 3], wp[k + 3], a3);
        }
        float bnv = fmaf(fmaxf((a0 + a1) + (a2 + a3), 0.f), sc, sh);

        // a2p = [send || recv] @ Wa + ba
        const float* __restrict__ rs = x + (size_t)is * D;
        const float* __restrict__ rr = x + (size_t)ir * D;
        float c0 = baj, c1 = 0.f, c2 = 0.f, c3 = 0.f;
#pragma unroll
        for (int k = 0; k < D; k += 4) {
            c0 = fmaf(rs[k + 0], wa[k + 0], c0);
            c1 = fmaf(rs[k + 1], wa[k + 1], c1);
            c2 = fmaf(rs[k + 2], wa[k + 2], c2);
            c3 = fmaf(rs[k + 3], wa[k + 3], c3);
        }
#pragma unroll
        for (int k = 0; k < D; k += 4) {
            c0 = fmaf(rr[k + 0], wa[D + k + 0], c0);
            c1 = fmaf(rr[k + 1], wa[D + k + 1], c1);
            c2 = fmaf(rr[k + 2], wa[D + k + 2], c2);
            c3 = fmaf(rr[k + 3], wa[D + k + 3], c3);
        }
        out[(size_t)e * D + lane] = bnv + (c0 + c1) + (c2 + c3);
    }
}

extern "C" void kernel_launch(void* const* d_in, const int* in_sizes, int n_in,
                              void* d_out, int out_size, void* d_ws, size_t ws_size,
                              hipStream_t stream) {
    const float* x       = (const float*)d_in[0];
    const float* pf      = (const float*)d_in[1];
    const int*   pidx    = (const int*)d_in[2];
    const float* W_atom  = (const float*)d_in[3];
    const float* b_atom  = (const float*)d_in[4];
    const float* g_atom  = (const float*)d_in[5];
    const float* be_atom = (const float*)d_in[6];
    const float* W_pair  = (const float*)d_in[7];
    const float* b_pair  = (const float*)d_in[8];
    const float* g_pair  = (const float*)d_in[9];
    const float* be_pair = (const float*)d_in[10];
    const float* W_a2p   = (const float*)d_in[11];
    const float* b_a2p   = (const float*)d_in[12];

    const int N = in_sizes[0] / D;
    const int E = in_sizes[1] / D;

    float* out_atom = (float*)d_out;
    float* out_pair = out_atom + (size_t)N * D;

    float* stats  = (float*)d_ws;     // 256 floats: atom sum/sq, pair sum/sq
    float* params = stats + 256;      // 256 floats: atom scale/shift, pair scale/shift

    hipMemsetAsync(d_ws, 0, 256 * sizeof(float), stream);

    gemm_relu_stats_kernel<<<512, 256, 0, stream>>>(x, W_atom, b_atom, N, stats);
    gemm_relu_stats_kernel<<<4096, 256, 0, stream>>>(pf, W_pair, b_pair, E, stats + 2 * D);
    finalize_stats_kernel<<<1, 128, 0, stream>>>(stats, g_atom, be_atom, g_pair, be_pair,
                                                 (float)N, (float)E, params);
    gemm_relu_bn_kernel<<<512, 256, 0, stream>>>(x, W_atom, b_atom, N, params, out_atom);
    pair_out_kernel<<<4096, 256, 0, stream>>>(pf, x, pidx, W_pair, b_pair,
                                              W_a2p, b_a2p, E, params + 2 * D, out_pair);
}

// Round 2
// 871.509 us; speedup vs baseline: 6.3790x; 6.3790x over previous
//
#include <hip/hip_runtime.h>

#define D 64
#define EPS 1e-5f

typedef __bf16 bf16x4 __attribute__((ext_vector_type(4)));
typedef __bf16 bf16x8 __attribute__((ext_vector_type(8)));
typedef float  f32x4  __attribute__((ext_vector_type(4)));

#define MFMA(a, b, c) __builtin_amdgcn_mfma_f32_16x16x32_bf16((a), (b), (c), 0, 0, 0)

// ---------------------------------------------------------------------------
// Pass 1 (shared atom/pair): h = relu(in @ W + b); accumulate per-feature
// sum / sumsq into global stats[128] via per-lane regs -> shfl -> atomics.
// Block tile: M=128 rows x N=64 x K=64. 4 waves; wave handles 2 m-tiles.
// ---------------------------------------------------------------------------
__global__ void __launch_bounds__(256) stats_gemm_kernel(
    const float* __restrict__ in, const float* __restrict__ W,
    const float* __restrict__ bias, int nrows, float* __restrict__ stats)
{
    __shared__ __bf16 As[128 * 72];   // +8 pad
    const int tid = threadIdx.x;
    const int lane = tid & 63, wv = tid >> 6;
    const int q = lane >> 4, l16 = lane & 15;

    // B fragments: Bf[ks][nt][j] = W[(ks*32 + q*8 + j)][nt*16 + l16]
    bf16x8 Bf[2][4];
#pragma unroll
    for (int ks = 0; ks < 2; ++ks)
#pragma unroll
      for (int nt = 0; nt < 4; ++nt)
#pragma unroll
        for (int j = 0; j < 8; ++j)
          Bf[ks][nt][j] = (__bf16)W[(ks * 32 + q * 8 + j) * 64 + nt * 16 + l16];

    float bc[4];
#pragma unroll
    for (int nt = 0; nt < 4; ++nt) bc[nt] = bias[nt * 16 + l16];

    float s[4] = {0.f, 0.f, 0.f, 0.f}, sq[4] = {0.f, 0.f, 0.f, 0.f};

    const int ntiles = (nrows + 127) >> 7;
    for (int t = blockIdx.x; t < ntiles; t += gridDim.x) {
        const int row0 = t << 7;
#pragma unroll
        for (int i = 0; i < 8; ++i) {
            int f = tid * 4 + i * 1024;
            int r = f >> 6, c = f & 63;
            int row = row0 + r;
            float4 v = (row < nrows) ? *(const float4*)(in + (size_t)row * 64 + c)
                                     : make_float4(0.f, 0.f, 0.f, 0.f);
            bf16x4 h;
            h[0] = (__bf16)v.x; h[1] = (__bf16)v.y;
            h[2] = (__bf16)v.z; h[3] = (__bf16)v.w;
            *(bf16x4*)&As[r * 72 + c] = h;
        }
        __syncthreads();

        f32x4 acc[2][4];
#pragma unroll
        for (int mt = 0; mt < 2; ++mt)
#pragma unroll
          for (int nt = 0; nt < 4; ++nt)
            acc[mt][nt] = (f32x4){0.f, 0.f, 0.f, 0.f};

#pragma unroll
        for (int mt = 0; mt < 2; ++mt) {
            int mrow = wv * 32 + mt * 16 + l16;
            bf16x8 a0 = *(const bf16x8*)&As[mrow * 72 + 0 + q * 8];
            bf16x8 a1 = *(const bf16x8*)&As[mrow * 72 + 32 + q * 8];
#pragma unroll
            for (int nt = 0; nt < 4; ++nt) {
                acc[mt][nt] = MFMA(a0, Bf[0][nt], acc[mt][nt]);
                acc[mt][nt] = MFMA(a1, Bf[1][nt], acc[mt][nt]);
            }
        }
        __syncthreads();

#pragma unroll
        for (int mt = 0; mt < 2; ++mt)
#pragma unroll
          for (int r = 0; r < 4; ++r) {
            int row = row0 + wv * 32 + mt * 16 + q * 4 + r;
            if (row < nrows) {
#pragma unroll
              for (int nt = 0; nt < 4; ++nt) {
                float h = fmaxf(acc[mt][nt][r] + bc[nt], 0.f);
                s[nt] += h;
                sq[nt] = fmaf(h, h, sq[nt]);
              }
            }
          }
    }

#pragma unroll
    for (int nt = 0; nt < 4; ++nt) {
        s[nt]  += __shfl_xor(s[nt], 16, 64);  s[nt]  += __shfl_xor(s[nt], 32, 64);
        sq[nt] += __shfl_xor(sq[nt], 16, 64); sq[nt] += __shfl_xor(sq[nt], 32, 64);
    }
    if (q == 0) {
#pragma unroll
        for (int nt = 0; nt < 4; ++nt) {
            atomicAdd(&stats[nt * 16 + l16], s[nt]);
            atomicAdd(&stats[64 + nt * 16 + l16], sq[nt]);
        }
    }
}

// ---------------------------------------------------------------------------
// scale = g*rsqrt(var+eps), shift = be - m*scale. t<64: atom, t>=64: pair.
// ---------------------------------------------------------------------------
__global__ void finalize_stats_kernel(
    const float* __restrict__ stats,
    const float* __restrict__ g_a, const float* __restrict__ be_a,
    const float* __restrict__ g_p, const float* __restrict__ be_p,
    float n_atom, float n_pair, float* __restrict__ params)
{
    const int t = threadIdx.x;
    const int j = t & 63;
    const bool p = t >= 64;
    const float* st = stats + (p ? 128 : 0);
    const float* g  = p ? g_p  : g_a;
    const float* be = p ? be_p : be_a;
    const float cnt = p ? n_pair : n_atom;
    float m = st[j] / cnt;
    float v = st[64 + j] / cnt - m * m;
    float sc = g[j] * rsqrtf(v + EPS);
    float sh = be[j] - m * sc;
    float* pr = params + (p ? 128 : 0);
    pr[j] = sc;
    pr[64 + j] = sh;
}

// ---------------------------------------------------------------------------
// Atom pass 2: recompute h = relu(x@W+b), apply affine, store fp32.
// Same tiling as stats kernel.
// ---------------------------------------------------------------------------
__global__ void __launch_bounds__(256) apply_atom_kernel(
    const float* __restrict__ in, const float* __restrict__ W,
    const float* __restrict__ bias, int nrows,
    const float* __restrict__ params, float* __restrict__ out)
{
    __shared__ __bf16 As[128 * 72];
    const int tid = threadIdx.x;
    const int lane = tid & 63, wv = tid >> 6;
    const int q = lane >> 4, l16 = lane & 15;

    bf16x8 Bf[2][4];
#pragma unroll
    for (int ks = 0; ks < 2; ++ks)
#pragma unroll
      for (int nt = 0; nt < 4; ++nt)
#pragma unroll
        for (int j = 0; j < 8; ++j)
          Bf[ks][nt][j] = (__bf16)W[(ks * 32 + q * 8 + j) * 64 + nt * 16 + l16];

    float bc[4], sc[4], sh[4];
#pragma unroll
    for (int nt = 0; nt < 4; ++nt) {
        bc[nt] = bias[nt * 16 + l16];
        sc[nt] = params[nt * 16 + l16];
        sh[nt] = params[64 + nt * 16 + l16];
    }

    const int ntiles = (nrows + 127) >> 7;
    for (int t = blockIdx.x; t < ntiles; t += gridDim.x) {
        const int row0 = t << 7;
#pragma unroll
        for (int i = 0; i < 8; ++i) {
            int f = tid * 4 + i * 1024;
            int r = f >> 6, c = f & 63;
            int row = row0 + r;
            float4 v = (row < nrows) ? *(const float4*)(in + (size_t)row * 64 + c)
                                     : make_float4(0.f, 0.f, 0.f, 0.f);
            bf16x4 h;
            h[0] = (__bf16)v.x; h[1] = (__bf16)v.y;
            h[2] = (__bf16)v.z; h[3] = (__bf16)v.w;
            *(bf16x4*)&As[r * 72 + c] = h;
        }
        __syncthreads();

        f32x4 acc[2][4];
#pragma unroll
        for (int mt = 0; mt < 2; ++mt)
#pragma unroll
          for (int nt = 0; nt < 4; ++nt)
            acc[mt][nt] = (f32x4){0.f, 0.f, 0.f, 0.f};

#pragma unroll
        for (int mt = 0; mt < 2; ++mt) {
            int mrow = wv * 32 + mt * 16 + l16;
            bf16x8 a0 = *(const bf16x8*)&As[mrow * 72 + 0 + q * 8];
            bf16x8 a1 = *(const bf16x8*)&As[mrow * 72 + 32 + q * 8];
#pragma unroll
            for (int nt = 0; nt < 4; ++nt) {
                acc[mt][nt] = MFMA(a0, Bf[0][nt], acc[mt][nt]);
                acc[mt][nt] = MFMA(a1, Bf[1][nt], acc[mt][nt]);
            }
        }
        __syncthreads();

#pragma unroll
        for (int mt = 0; mt < 2; ++mt)
#pragma unroll
          for (int r = 0; r < 4; ++r) {
            int row = row0 + wv * 32 + mt * 16 + q * 4 + r;
            if (row < nrows) {
#pragma unroll
              for (int nt = 0; nt < 4; ++nt) {
                float h = fmaxf(acc[mt][nt][r] + bc[nt], 0.f);
                out[(size_t)row * 64 + nt * 16 + l16] = fmaf(h, sc[nt], sh[nt]);
              }
            }
          }
    }
}

// ---------------------------------------------------------------------------
// Pair pass 2: out[e] = affine(relu(pf@Wp+bp)) + [x[send]||x[recv]] @ Wa + ba
// Block tile M=64 edges. Wave w owns m-tile w (16 edges), all 64 cols.
// Gather: 8 threads per x-row (fp32 global -> bf16 LDS).
// ---------------------------------------------------------------------------
__global__ void __launch_bounds__(256) pair_apply_kernel(
    const float* __restrict__ pf, const float* __restrict__ x,
    const int* __restrict__ pidx,
    const float* __restrict__ Wp, const float* __restrict__ bp,
    const float* __restrict__ Wa, const float* __restrict__ ba,
    int E, const float* __restrict__ params, float* __restrict__ out)
{
    __shared__ __bf16 A1[64 * 72];    // pf tile   (K=64)
    __shared__ __bf16 A2[64 * 136];   // gather tile (K=128)
    const int tid = threadIdx.x;
    const int lane = tid & 63, wv = tid >> 6;
    const int q = lane >> 4, l16 = lane & 15;

    bf16x8 B1[2][4];
#pragma unroll
    for (int ks = 0; ks < 2; ++ks)
#pragma unroll
      for (int nt = 0; nt < 4; ++nt)
#pragma unroll
        for (int j = 0; j < 8; ++j)
          B1[ks][nt][j] = (__bf16)Wp[(ks * 32 + q * 8 + j) * 64 + nt * 16 + l16];

    bf16x8 B2[4][4];
#pragma unroll
    for (int ks = 0; ks < 4; ++ks)
#pragma unroll
      for (int nt = 0; nt < 4; ++nt)
#pragma unroll
        for (int j = 0; j < 8; ++j)
          B2[ks][nt][j] = (__bf16)Wa[(ks * 32 + q * 8 + j) * 64 + nt * 16 + l16];

    float bpc[4], bac[4], sc[4], sh[4];
#pragma unroll
    for (int nt = 0; nt < 4; ++nt) {
        bpc[nt] = bp[nt * 16 + l16];
        bac[nt] = ba[nt * 16 + l16];
        sc[nt]  = params[nt * 16 + l16];
        sh[nt]  = params[64 + nt * 16 + l16];
    }

    const int ntiles = E >> 6;   // E divisible by 64
    for (int t = blockIdx.x; t < ntiles; t += gridDim.x) {
        const int e0 = t << 6;
        // stage pf tile (64 x 64 fp32 -> bf16)
#pragma unroll
        for (int i = 0; i < 4; ++i) {
            int f = tid * 4 + i * 1024;
            int r = f >> 6, c = f & 63;
            float4 v = *(const float4*)(pf + (size_t)(e0 + r) * 64 + c);
            bf16x4 h;
            h[0] = (__bf16)v.x; h[1] = (__bf16)v.y;
            h[2] = (__bf16)v.z; h[3] = (__bf16)v.w;
            *(bf16x4*)&A1[r * 72 + c] = h;
        }
        // stage gathered x rows: 128 row-halves (64 edges x {send,recv})
        {
            const int sub = tid & 7;
            for (int g = tid >> 3; g < 128; g += 32) {
                int el = g >> 1, half = g & 1;
                int idx = pidx[half * E + e0 + el];
                const float* src = x + (size_t)idx * 64 + sub * 8;
                float4 v0 = *(const float4*)(src);
                float4 v1 = *(const float4*)(src + 4);
                bf16x8 h;
                h[0] = (__bf16)v0.x; h[1] = (__bf16)v0.y;
                h[2] = (__bf16)v0.z; h[3] = (__bf16)v0.w;
                h[4] = (__bf16)v1.x; h[5] = (__bf16)v1.y;
                h[6] = (__bf16)v1.z; h[7] = (__bf16)v1.w;
                *(bf16x8*)&A2[el * 136 + half * 64 + sub * 8] = h;
            }
        }
        __syncthreads();

        f32x4 acc1[4], acc2[4];
#pragma unroll
        for (int nt = 0; nt < 4; ++nt) {
            acc1[nt] = (f32x4){0.f, 0.f, 0.f, 0.f};
            acc2[nt] = (f32x4){0.f, 0.f, 0.f, 0.f};
        }

        const int mrow = wv * 16 + l16;
        {
            bf16x8 a0 = *(const bf16x8*)&A1[mrow * 72 + 0 + q * 8];
            bf16x8 a1 = *(const bf16x8*)&A1[mrow * 72 + 32 + q * 8];
#pragma unroll
            for (int nt = 0; nt < 4; ++nt) {
                acc1[nt] = MFMA(a0, B1[0][nt], acc1[nt]);
                acc1[nt] = MFMA(a1, B1[1][nt], acc1[nt]);
            }
        }
#pragma unroll
        for (int ks = 0; ks < 4; ++ks) {
            bf16x8 a = *(const bf16x8*)&A2[mrow * 136 + ks * 32 + q * 8];
#pragma unroll
            for (int nt = 0; nt < 4; ++nt)
                acc2[nt] = MFMA(a, B2[ks][nt], acc2[nt]);
        }
        __syncthreads();

#pragma unroll
        for (int r = 0; r < 4; ++r) {
            int row = e0 + wv * 16 + q * 4 + r;
#pragma unroll
            for (int nt = 0; nt < 4; ++nt) {
                float h = fmaxf(acc1[nt][r] + bpc[nt], 0.f);
                float val = fmaf(h, sc[nt], sh[nt]) + acc2[nt][r] + bac[nt];
                out[(size_t)row * 64 + nt * 16 + l16] = val;
            }
        }
    }
}

extern "C" void kernel_launch(void* const* d_in, const int* in_sizes, int n_in,
                              void* d_out, int out_size, void* d_ws, size_t ws_size,
                              hipStream_t stream) {
    const float* x       = (const float*)d_in[0];
    const float* pf      = (const float*)d_in[1];
    const int*   pidx    = (const int*)d_in[2];
    const float* W_atom  = (const float*)d_in[3];
    const float* b_atom  = (const float*)d_in[4];
    const float* g_atom  = (const float*)d_in[5];
    const float* be_atom = (const float*)d_in[6];
    const float* W_pair  = (const float*)d_in[7];
    const float* b_pair  = (const float*)d_in[8];
    const float* g_pair  = (const float*)d_in[9];
    const float* be_pair = (const float*)d_in[10];
    const float* W_a2p   = (const float*)d_in[11];
    const float* b_a2p   = (const float*)d_in[12];

    const int N = in_sizes[0] / D;
    const int E = in_sizes[1] / D;

    float* out_atom = (float*)d_out;
    float* out_pair = out_atom + (size_t)N * D;

    float* stats  = (float*)d_ws;     // [256]: atom sum/sq @0, pair sum/sq @128
    float* params = stats + 256;      // [256]: atom scale/shift @0, pair @128

    hipMemsetAsync(d_ws, 0, 256 * sizeof(float), stream);

    int at = (N + 127) / 128, pt = (E + 127) / 128;
    int atg = at < 1024 ? at : 1024;
    int ptg = pt < 2048 ? pt : 2048;

    stats_gemm_kernel<<<atg, 256, 0, stream>>>(x, W_atom, b_atom, N, stats);
    stats_gemm_kernel<<<ptg, 256, 0, stream>>>(pf, W_pair, b_pair, E, stats + 128);
    finalize_stats_kernel<<<1, 128, 0, stream>>>(stats, g_atom, be_atom, g_pair, be_pair,
                                                 (float)N, (float)E, params);
    apply_atom_kernel<<<atg, 256, 0, stream>>>(x, W_atom, b_atom, N, params, out_atom);

    int pag = (E / 64) < 2048 ? (E / 64) : 2048;
    pair_apply_kernel<<<pag, 256, 0, stream>>>(pf, x, pidx, W_pair, b_pair,
                                               W_a2p, b_a2p, E, params + 128, out_pair);
}